// Round 1
// baseline (1186.647 us; speedup 1.0000x reference)
//
#include <hip/hip_runtime.h>
#include <math.h>

#define NN 50000
#define NE 800000
#define IN_CH 10
#define NEGS 0.2f
#define LNEPS 1e-5f

__device__ __forceinline__ float red32(float v) {
    v += __shfl_xor(v, 1);  v += __shfl_xor(v, 2);  v += __shfl_xor(v, 4);
    v += __shfl_xor(v, 8);  v += __shfl_xor(v, 16);
    return v;   // sum within each aligned 32-lane group of the 64-wide wave
}
__device__ __forceinline__ float red64(float v) {
    v = red32(v); v += __shfl_xor(v, 32);
    return v;
}

// ---- layer 1 ----

// xl = x @ W1l, xr = x @ W1r   [N,128] each; block=256 -> 2 nodes
__global__ __launch_bounds__(256) void k_proj1(
    const float* __restrict__ x, const float* __restrict__ Wl,
    const float* __restrict__ Wr, float* __restrict__ xl, float* __restrict__ xr) {
    int j = threadIdx.x & 127;
    int n = blockIdx.x * 2 + (threadIdx.x >> 7);
    if (n >= NN) return;
    float al = 0.f, ar = 0.f;
#pragma unroll
    for (int k = 0; k < IN_CH; ++k) {
        float xv = x[n * IN_CH + k];
        al = fmaf(xv, Wl[k * 128 + j], al);
        ar = fmaf(xv, Wr[k * 128 + j], ar);
    }
    xl[n * 128 + j] = al;
    xr[n * 128 + j] = ar;
}

// per edge: logit[e,h] -> expv[e,h], denom[dst,h] += expv. block=256 -> 2 edges x 128 lanes
__global__ __launch_bounds__(256) void k_edge1(
    const int* __restrict__ ei, const float* __restrict__ ea,
    const float* __restrict__ xl, const float* __restrict__ xr,
    const float* __restrict__ We, const float* __restrict__ att,
    float* __restrict__ expv, float* __restrict__ den) {
    int t = threadIdx.x & 127;               // h = t>>5, c = t&31
    int e = blockIdx.x * 2 + (threadIdx.x >> 7);
    if (e >= NE) return;
    int s = ei[e], d = ei[NE + e];
    float v = xl[d * 128 + t] + xr[s * 128 + t] + ea[e] * We[t];
    v = v > 0.f ? v : NEGS * v;
    float p = red32(v * att[t]);             // logit for head t>>5
    if ((t & 31) == 0) {
        float ex = expf(p);                  // max-shift skipped: alpha invariant, |logit| small
        int h = t >> 5;
        expv[e * 4 + h] = ex;
        unsafeAtomicAdd(&den[d * 4 + h], ex);
    }
}

// un[dst] += expv[e,h] * xr[src]   block=256 -> 2 edges x 128 lanes
__global__ __launch_bounds__(256) void k_agg1(
    const int* __restrict__ ei, const float* __restrict__ expv,
    const float* __restrict__ xr, float* __restrict__ un) {
    int t = threadIdx.x & 127;
    int e = blockIdx.x * 2 + (threadIdx.x >> 7);
    if (e >= NE) return;
    int s = ei[e], d = ei[NE + e];
    float a = expv[e * 4 + (t >> 5)];
    unsafeAtomicAdd(&un[d * 128 + t], a * xr[s * 128 + t]);
}

// h1 = elu(LN(un/den + b1))   wave per node, 2 ch per lane
__global__ __launch_bounds__(256) void k_norm1(
    const float* __restrict__ un, const float* __restrict__ den,
    const float* __restrict__ bias, const float* __restrict__ g,
    const float* __restrict__ b, float* __restrict__ h1) {
    int lane = threadIdx.x & 63;
    int n = blockIdx.x * 4 + (threadIdx.x >> 6);
    if (n >= NN) return;
    int c0 = lane * 2;
    float dd = den[n * 4 + (c0 >> 5)];
    float2 u = *(const float2*)&un[n * 128 + c0];
    float a0 = dd > 0.f ? u.x / dd : 0.f;
    float a1 = dd > 0.f ? u.y / dd : 0.f;
    a0 += bias[c0]; a1 += bias[c0 + 1];
    float mu = red64(a0 + a1) * (1.f / 128.f);
    float d0 = a0 - mu, d1 = a1 - mu;
    float var = red64(d0 * d0 + d1 * d1) * (1.f / 128.f);
    float rs = rsqrtf(var + LNEPS);
    float o0 = d0 * rs * g[c0] + b[c0];
    float o1 = d1 * rs * g[c0 + 1] + b[c0 + 1];
    o0 = o0 > 0.f ? o0 : expf(o0) - 1.f;
    o1 = o1 > 0.f ? o1 : expf(o1) - 1.f;
    h1[n * 128 + c0] = o0;
    h1[n * 128 + c0 + 1] = o1;
}

// ---- layer 2 ----

// xl2 = h1 @ W2l, xr2 = h1 @ W2r  [N,64]; block=256 -> 4 nodes x 64 lanes
__global__ __launch_bounds__(256) void k_proj2(
    const float* __restrict__ h1, const float* __restrict__ Wl,
    const float* __restrict__ Wr, float* __restrict__ xl2, float* __restrict__ xr2) {
    __shared__ float sh[4][128];
    int grp = threadIdx.x >> 6;
    int c = threadIdx.x & 63;
    int n = blockIdx.x * 4 + grp;
    if (n < NN) {
        sh[grp][c] = h1[n * 128 + c];
        sh[grp][c + 64] = h1[n * 128 + c + 64];
    }
    __syncthreads();
    if (n >= NN) return;
    float al = 0.f, ar = 0.f;
#pragma unroll 8
    for (int k = 0; k < 128; ++k) {
        float hv = sh[grp][k];
        al = fmaf(hv, Wl[k * 64 + c], al);
        ar = fmaf(hv, Wr[k * 64 + c], ar);
    }
    xl2[n * 64 + c] = al;
    xr2[n * 64 + c] = ar;
}

// per edge logit2 -> expv2, den2   block=256 -> 4 edges x 64 lanes
__global__ __launch_bounds__(256) void k_edge2(
    const int* __restrict__ ei, const float* __restrict__ ea,
    const float* __restrict__ xl2, const float* __restrict__ xr2,
    const float* __restrict__ We, const float* __restrict__ att,
    float* __restrict__ expv2, float* __restrict__ den2) {
    int c = threadIdx.x & 63;
    int e = blockIdx.x * 4 + (threadIdx.x >> 6);
    if (e >= NE) return;
    int s = ei[e], d = ei[NE + e];
    float v = xl2[d * 64 + c] + xr2[s * 64 + c] + ea[e] * We[c];
    v = v > 0.f ? v : NEGS * v;
    float p = red64(v * att[c]);
    if (c == 0) {
        float ex = expf(p);
        expv2[e] = ex;
        unsafeAtomicAdd(&den2[d], ex);
    }
}

// out_acc[dst] += expv2[e] * xr2[src]   block=256 -> 4 edges x 64 lanes
__global__ __launch_bounds__(256) void k_agg2(
    const int* __restrict__ ei, const float* __restrict__ expv2,
    const float* __restrict__ xr2, float* __restrict__ acc) {
    int c = threadIdx.x & 63;
    int e = blockIdx.x * 4 + (threadIdx.x >> 6);
    if (e >= NE) return;
    int s = ei[e], d = ei[NE + e];
    unsafeAtomicAdd(&acc[d * 64 + c], expv2[e] * xr2[s * 64 + c]);
}

// out = elu(LN(acc/den2 + b2)) in place; wave per node, 1 ch per lane
__global__ __launch_bounds__(256) void k_norm2(
    float* __restrict__ acc, const float* __restrict__ den2,
    const float* __restrict__ bias, const float* __restrict__ g,
    const float* __restrict__ b) {
    int c = threadIdx.x & 63;
    int n = blockIdx.x * 4 + (threadIdx.x >> 6);
    if (n >= NN) return;
    float dd = den2[n];
    float a = dd > 0.f ? acc[n * 64 + c] / dd : 0.f;
    a += bias[c];
    float mu = red64(a) * (1.f / 64.f);
    float df = a - mu;
    float var = red64(df * df) * (1.f / 64.f);
    float rs = rsqrtf(var + LNEPS);
    float o = df * rs * g[c] + b[c];
    o = o > 0.f ? o : expf(o) - 1.f;
    acc[n * 64 + c] = o;
}

extern "C" void kernel_launch(void* const* d_in, const int* in_sizes, int n_in,
                              void* d_out, int out_size, void* d_ws, size_t ws_size,
                              hipStream_t stream) {
    const float* x    = (const float*)d_in[0];
    const float* ea   = (const float*)d_in[1];
    const float* W1l  = (const float*)d_in[2];
    const float* W1r  = (const float*)d_in[3];
    const float* W1e  = (const float*)d_in[4];
    const float* att1 = (const float*)d_in[5];
    const float* b1   = (const float*)d_in[6];
    const float* ln1g = (const float*)d_in[7];
    const float* ln1b = (const float*)d_in[8];
    const float* W2l  = (const float*)d_in[9];
    const float* W2r  = (const float*)d_in[10];
    const float* W2e  = (const float*)d_in[11];
    const float* att2 = (const float*)d_in[12];
    const float* b2   = (const float*)d_in[13];
    const float* ln2g = (const float*)d_in[14];
    const float* ln2b = (const float*)d_in[15];
    const int*   ei   = (const int*)d_in[16];
    float* out = (float*)d_out;
    float* ws  = (float*)d_ws;

    const size_t A = (size_t)NN * 128;
    float* xl1 = ws;
    float* xr1 = ws + A;
    float* un1 = ws + 2 * A;
    float* h1  = ws + 3 * A;
    float* ex1 = ws + 4 * A;                    // E*4
    float* dn1 = ex1 + (size_t)NE * 4;          // N*4
    float* xl2 = dn1 + (size_t)NN * 4;          // N*64
    float* xr2 = xl2 + (size_t)NN * 64;         // N*64
    float* ex2 = xr2 + (size_t)NN * 64;         // E
    float* dn2 = ex2 + (size_t)NE;              // N

    hipMemsetAsync(un1, 0, A * sizeof(float), stream);
    hipMemsetAsync(dn1, 0, (size_t)NN * 4 * sizeof(float), stream);
    hipMemsetAsync(dn2, 0, (size_t)NN * sizeof(float), stream);
    hipMemsetAsync(out, 0, (size_t)NN * 64 * sizeof(float), stream);

    k_proj1<<<NN / 2, 256, 0, stream>>>(x, W1l, W1r, xl1, xr1);
    k_edge1<<<NE / 2, 256, 0, stream>>>(ei, ea, xl1, xr1, W1e, att1, ex1, dn1);
    k_agg1<<<NE / 2, 256, 0, stream>>>(ei, ex1, xr1, un1);
    k_norm1<<<NN / 4, 256, 0, stream>>>(un1, dn1, b1, ln1g, ln1b, h1);
    k_proj2<<<NN / 4, 256, 0, stream>>>(h1, W2l, W2r, xl2, xr2);
    k_edge2<<<NE / 4, 256, 0, stream>>>(ei, ea, xl2, xr2, W2e, att2, ex2, dn2);
    k_agg2<<<NE / 4, 256, 0, stream>>>(ei, ex2, xr2, out);
    k_norm2<<<NN / 4, 256, 0, stream>>>(out, dn2, b2, ln2g, ln2b);
}

// Round 2
// 533.721 us; speedup vs baseline: 2.2233x; 2.2233x over previous
//
#include <hip/hip_runtime.h>
#include <math.h>

#define NN 50000
#define NE 800000
#define IN_CH 10
#define NEGS 0.2f
#define LNEPS 1e-5f
#define SCAN_E 1024   // elements per scan block
#define NB 49         // ceil(NN / SCAN_E)

__device__ __forceinline__ float red16(float v) {
    v += __shfl_xor(v, 1);  v += __shfl_xor(v, 2);
    v += __shfl_xor(v, 4);  v += __shfl_xor(v, 8);
    return v;   // sum within aligned 16-lane group (one head, 2ch/lane)
}
__device__ __forceinline__ float red64(float v) {
    v += __shfl_xor(v, 1);  v += __shfl_xor(v, 2);  v += __shfl_xor(v, 4);
    v += __shfl_xor(v, 8);  v += __shfl_xor(v, 16); v += __shfl_xor(v, 32);
    return v;
}

// ---------- projections ----------

// xl = x @ W1l, xr = x @ W1r   [N,128]; block=256 -> 2 nodes x 128 lanes
__global__ __launch_bounds__(256) void k_proj1(
    const float* __restrict__ x, const float* __restrict__ Wl,
    const float* __restrict__ Wr, float* __restrict__ xl, float* __restrict__ xr) {
    int j = threadIdx.x & 127;
    int n = blockIdx.x * 2 + (threadIdx.x >> 7);
    if (n >= NN) return;
    float al = 0.f, ar = 0.f;
#pragma unroll
    for (int k = 0; k < IN_CH; ++k) {
        float xv = x[n * IN_CH + k];
        al = fmaf(xv, Wl[k * 128 + j], al);
        ar = fmaf(xv, Wr[k * 128 + j], ar);
    }
    xl[n * 128 + j] = al;
    xr[n * 128 + j] = ar;
}

// xl2 = h1 @ W2l, xr2 = h1 @ W2r  [N,64]; block=256 -> 4 nodes x 64 lanes
__global__ __launch_bounds__(256) void k_proj2(
    const float* __restrict__ h1, const float* __restrict__ Wl,
    const float* __restrict__ Wr, float* __restrict__ xl2, float* __restrict__ xr2) {
    __shared__ float sh[4][128];
    int grp = threadIdx.x >> 6;
    int c = threadIdx.x & 63;
    int n = blockIdx.x * 4 + grp;
    if (n < NN) {
        sh[grp][c] = h1[n * 128 + c];
        sh[grp][c + 64] = h1[n * 128 + c + 64];
    }
    __syncthreads();
    if (n >= NN) return;
    float al = 0.f, ar = 0.f;
#pragma unroll 8
    for (int k = 0; k < 128; ++k) {
        float hv = sh[grp][k];
        al = fmaf(hv, Wl[k * 64 + c], al);
        ar = fmaf(hv, Wr[k * 64 + c], ar);
    }
    xl2[n * 64 + c] = al;
    xr2[n * 64 + c] = ar;
}

// ---------- CSR build (edges grouped by dst) ----------

__global__ __launch_bounds__(256) void k_deg(const int* __restrict__ ei, int* __restrict__ deg) {
    int e = blockIdx.x * 256 + threadIdx.x;
    if (e < NE) atomicAdd(&deg[ei[NE + e]], 1);
}

// per-block exclusive scan of deg into rowstart (local), block totals into partial
__global__ __launch_bounds__(256) void k_scan_block(
    const int* __restrict__ deg, int* __restrict__ rowstart, int* __restrict__ partial) {
    __shared__ int sh[256];
    int t = threadIdx.x;
    int base = blockIdx.x * SCAN_E + t * 4;
    int d0 = 0, d1 = 0, d2 = 0, d3 = 0;
    if (base + 0 < NN) d0 = deg[base + 0];
    if (base + 1 < NN) d1 = deg[base + 1];
    if (base + 2 < NN) d2 = deg[base + 2];
    if (base + 3 < NN) d3 = deg[base + 3];
    int mysum = d0 + d1 + d2 + d3;
    sh[t] = mysum;
    __syncthreads();
    for (int off = 1; off < 256; off <<= 1) {
        int v = (t >= off) ? sh[t - off] : 0;
        __syncthreads();
        sh[t] += v;
        __syncthreads();
    }
    int ex = sh[t] - mysum;   // exclusive within block
    if (base + 0 < NN) rowstart[base + 0] = ex;
    if (base + 1 < NN) rowstart[base + 1] = ex + d0;
    if (base + 2 < NN) rowstart[base + 2] = ex + d0 + d1;
    if (base + 3 < NN) rowstart[base + 3] = ex + d0 + d1 + d2;
    if (t == 255) partial[blockIdx.x] = sh[255];
}

// add block offsets; init cursor; set rowstart[NN]=NE
__global__ __launch_bounds__(256) void k_scan_add(
    const int* __restrict__ partial, int* __restrict__ rowstart, int* __restrict__ cursor) {
    __shared__ int off;
    int t = threadIdx.x, bI = blockIdx.x;
    if (t == 0) {
        int s = 0;
        for (int k = 0; k < bI; ++k) s += partial[k];
        off = s;
    }
    __syncthreads();
    int base = bI * SCAN_E + t * 4;
#pragma unroll
    for (int i = 0; i < 4; ++i) {
        int idx = base + i;
        if (idx < NN) {
            int v = rowstart[idx] + off;
            rowstart[idx] = v;
            cursor[idx] = v;
        }
    }
    if (bI == 0 && t == 0) rowstart[NN] = NE;
}

__global__ __launch_bounds__(256) void k_scatter(
    const int* __restrict__ ei, const float* __restrict__ ea,
    int* __restrict__ cursor, int* __restrict__ csrc, float* __restrict__ cea) {
    int e = blockIdx.x * 256 + threadIdx.x;
    if (e >= NE) return;
    int d = ei[NE + e];
    int p = atomicAdd(&cursor[d], 1);
    csrc[p] = ei[e];
    cea[p] = ea[e];
}

// ---------- fused per-node GATv2 layers ----------

// layer 1: wave per node, 2 ch/lane (c0=2*lane); edge loop gathers xr[src]
__global__ __launch_bounds__(256) void k_fused1(
    const int* __restrict__ rs, const int* __restrict__ csrc, const float* __restrict__ cea,
    const float* __restrict__ xl, const float* __restrict__ xr,
    const float* __restrict__ We, const float* __restrict__ att,
    const float* __restrict__ bias, const float* __restrict__ g,
    const float* __restrict__ b, float* __restrict__ h1) {
    int lane = threadIdx.x & 63;
    int n = blockIdx.x * 4 + (threadIdx.x >> 6);
    if (n >= NN) return;
    int c0 = lane * 2;
    float2 xld = *(const float2*)&xl[n * 128 + c0];
    float2 Wev = *(const float2*)&We[c0];
    float2 atv = *(const float2*)&att[c0];
    int beg = rs[n], end = rs[n + 1];
    float acc0 = 0.f, acc1 = 0.f, den = 0.f;
    for (int p = beg; p < end; ++p) {
        int s = csrc[p];
        float eav = cea[p];
        float2 xrv = *(const float2*)&xr[s * 128 + c0];
        float v0 = xld.x + xrv.x + eav * Wev.x;
        float v1 = xld.y + xrv.y + eav * Wev.y;
        v0 = v0 > 0.f ? v0 : NEGS * v0;
        v1 = v1 > 0.f ? v1 : NEGS * v1;
        float lg = red16(v0 * atv.x + v1 * atv.y);   // head logit (head = lane>>4)
        float el = expf(lg);                          // max-shift skipped: alpha invariant
        den += el;
        acc0 = fmaf(el, xrv.x, acc0);
        acc1 = fmaf(el, xrv.y, acc1);
    }
    float a0 = den > 0.f ? acc0 / den : 0.f;
    float a1 = den > 0.f ? acc1 / den : 0.f;
    float2 bv = *(const float2*)&bias[c0];
    a0 += bv.x; a1 += bv.y;
    float mu = red64(a0 + a1) * (1.f / 128.f);
    float d0 = a0 - mu, d1 = a1 - mu;
    float var = red64(d0 * d0 + d1 * d1) * (1.f / 128.f);
    float rsq = rsqrtf(var + LNEPS);
    float2 gv = *(const float2*)&g[c0];
    float2 bb = *(const float2*)&b[c0];
    float o0 = d0 * rsq * gv.x + bb.x;
    float o1 = d1 * rsq * gv.y + bb.y;
    o0 = o0 > 0.f ? o0 : expf(o0) - 1.f;
    o1 = o1 > 0.f ? o1 : expf(o1) - 1.f;
    *(float2*)&h1[n * 128 + c0] = make_float2(o0, o1);
}

// layer 2: wave per node, 1 ch/lane, single head
__global__ __launch_bounds__(256) void k_fused2(
    const int* __restrict__ rs, const int* __restrict__ csrc, const float* __restrict__ cea,
    const float* __restrict__ xl2, const float* __restrict__ xr2,
    const float* __restrict__ We, const float* __restrict__ att,
    const float* __restrict__ bias, const float* __restrict__ g,
    const float* __restrict__ b, float* __restrict__ out) {
    int lane = threadIdx.x & 63;
    int n = blockIdx.x * 4 + (threadIdx.x >> 6);
    if (n >= NN) return;
    float xld = xl2[n * 64 + lane];
    float Wev = We[lane], atv = att[lane];
    int beg = rs[n], end = rs[n + 1];
    float acc = 0.f, den = 0.f;
    for (int p = beg; p < end; ++p) {
        int s = csrc[p];
        float eav = cea[p];
        float xrv = xr2[s * 64 + lane];
        float v = xld + xrv + eav * Wev;
        v = v > 0.f ? v : NEGS * v;
        float lg = red64(v * atv);
        float el = expf(lg);
        den += el;
        acc = fmaf(el, xrv, acc);
    }
    float a = den > 0.f ? acc / den : 0.f;
    a += bias[lane];
    float mu = red64(a) * (1.f / 64.f);
    float df = a - mu;
    float var = red64(df * df) * (1.f / 64.f);
    float rsq = rsqrtf(var + LNEPS);
    float o = df * rsq * g[lane] + b[lane];
    o = o > 0.f ? o : expf(o) - 1.f;
    out[n * 64 + lane] = o;
}

extern "C" void kernel_launch(void* const* d_in, const int* in_sizes, int n_in,
                              void* d_out, int out_size, void* d_ws, size_t ws_size,
                              hipStream_t stream) {
    const float* x    = (const float*)d_in[0];
    const float* ea   = (const float*)d_in[1];
    const float* W1l  = (const float*)d_in[2];
    const float* W1r  = (const float*)d_in[3];
    const float* W1e  = (const float*)d_in[4];
    const float* att1 = (const float*)d_in[5];
    const float* b1   = (const float*)d_in[6];
    const float* ln1g = (const float*)d_in[7];
    const float* ln1b = (const float*)d_in[8];
    const float* W2l  = (const float*)d_in[9];
    const float* W2r  = (const float*)d_in[10];
    const float* W2e  = (const float*)d_in[11];
    const float* att2 = (const float*)d_in[12];
    const float* b2   = (const float*)d_in[13];
    const float* ln2g = (const float*)d_in[14];
    const float* ln2b = (const float*)d_in[15];
    const int*   ei   = (const int*)d_in[16];
    float* out = (float*)d_out;
    float* ws  = (float*)d_ws;

    const size_t A = (size_t)NN * 128;
    float* xl1 = ws;                       // N*128
    float* xr1 = ws + A;                   // N*128
    float* h1  = ws + 2 * A;               // N*128
    float* xl2 = ws + 3 * A;               // N*64
    float* xr2 = xl2 + (size_t)NN * 64;    // N*64
    float* cea = xr2 + (size_t)NN * 64;    // NE
    int* csrc    = (int*)(cea + (size_t)NE);   // NE
    int* deg     = csrc + (size_t)NE;          // NN
    int* rowstart= deg + NN;                   // NN+1
    int* cursor  = rowstart + NN + 1;          // NN
    int* partial = cursor + NN;                // NB

    hipMemsetAsync(deg, 0, NN * sizeof(int), stream);

    k_proj1<<<NN / 2, 256, 0, stream>>>(x, W1l, W1r, xl1, xr1);
    k_deg<<<(NE + 255) / 256, 256, 0, stream>>>(ei, deg);
    k_scan_block<<<NB, 256, 0, stream>>>(deg, rowstart, partial);
    k_scan_add<<<NB, 256, 0, stream>>>(partial, rowstart, cursor);
    k_scatter<<<(NE + 255) / 256, 256, 0, stream>>>(ei, ea, cursor, csrc, cea);

    k_fused1<<<(NN + 3) / 4, 256, 0, stream>>>(rowstart, csrc, cea, xl1, xr1,
                                               W1e, att1, b1, ln1g, ln1b, h1);
    k_proj2<<<(NN + 3) / 4, 256, 0, stream>>>(h1, W2l, W2r, xl2, xr2);
    k_fused2<<<(NN + 3) / 4, 256, 0, stream>>>(rowstart, csrc, cea, xl2, xr2,
                                               W2e, att2, b2, ln2g, ln2b, out);
}

// Round 3
// 418.707 us; speedup vs baseline: 2.8341x; 1.2747x over previous
//
#include <hip/hip_runtime.h>
#include <math.h>

#define NN 50000
#define NE 800000
#define IN_CH 10
#define NEGS 0.2f
#define LNEPS 1e-5f
#define SCAN_E 1024   // elements per scan block
#define NB 49         // ceil(NN / SCAN_E)

__device__ __forceinline__ float red16g(float v) {   // sum within aligned 16-lane group
    v += __shfl_xor(v, 1);  v += __shfl_xor(v, 2);
    v += __shfl_xor(v, 4);  v += __shfl_xor(v, 8);
    return v;
}
__device__ __forceinline__ float red32g(float v) {   // sum within aligned 32-lane group
    v = red16g(v); v += __shfl_xor(v, 16);
    return v;
}
__device__ __forceinline__ float lrelu(float v) { return v > 0.f ? v : NEGS * v; }

// ---------- projections ----------

// xl = x @ W1l, xr = x @ W1r   [N,128]; block=256 -> 2 nodes x 128 lanes
__global__ __launch_bounds__(256) void k_proj1(
    const float* __restrict__ x, const float* __restrict__ Wl,
    const float* __restrict__ Wr, float* __restrict__ xl, float* __restrict__ xr) {
    int j = threadIdx.x & 127;
    int n = blockIdx.x * 2 + (threadIdx.x >> 7);
    if (n >= NN) return;
    float al = 0.f, ar = 0.f;
#pragma unroll
    for (int k = 0; k < IN_CH; ++k) {
        float xv = x[n * IN_CH + k];
        al = fmaf(xv, Wl[k * 128 + j], al);
        ar = fmaf(xv, Wr[k * 128 + j], ar);
    }
    xl[n * 128 + j] = al;
    xr[n * 128 + j] = ar;
}

// xl2 = h1 @ W2l, xr2 = h1 @ W2r  [N,64]; block=256 -> 4 nodes x 64 lanes
__global__ __launch_bounds__(256) void k_proj2(
    const float* __restrict__ h1, const float* __restrict__ Wl,
    const float* __restrict__ Wr, float* __restrict__ xl2, float* __restrict__ xr2) {
    __shared__ float sh[4][128];
    int grp = threadIdx.x >> 6;
    int c = threadIdx.x & 63;
    int n = blockIdx.x * 4 + grp;
    if (n < NN) {
        sh[grp][c] = h1[n * 128 + c];
        sh[grp][c + 64] = h1[n * 128 + c + 64];
    }
    __syncthreads();
    if (n >= NN) return;
    float al = 0.f, ar = 0.f;
#pragma unroll 8
    for (int k = 0; k < 128; ++k) {
        float hv = sh[grp][k];
        al = fmaf(hv, Wl[k * 64 + c], al);
        ar = fmaf(hv, Wr[k * 64 + c], ar);
    }
    xl2[n * 64 + c] = al;
    xr2[n * 64 + c] = ar;
}

// ---------- CSR build (edges grouped by dst; payload packed as {src, ea}) ----------

__global__ __launch_bounds__(256) void k_deg(const int* __restrict__ ei, int* __restrict__ deg) {
    int e = blockIdx.x * 256 + threadIdx.x;
    if (e < NE) atomicAdd(&deg[ei[NE + e]], 1);
}

__global__ __launch_bounds__(256) void k_scan_block(
    const int* __restrict__ deg, int* __restrict__ rowstart, int* __restrict__ partial) {
    __shared__ int sh[256];
    int t = threadIdx.x;
    int base = blockIdx.x * SCAN_E + t * 4;
    int d0 = 0, d1 = 0, d2 = 0, d3 = 0;
    if (base + 0 < NN) d0 = deg[base + 0];
    if (base + 1 < NN) d1 = deg[base + 1];
    if (base + 2 < NN) d2 = deg[base + 2];
    if (base + 3 < NN) d3 = deg[base + 3];
    int mysum = d0 + d1 + d2 + d3;
    sh[t] = mysum;
    __syncthreads();
    for (int off = 1; off < 256; off <<= 1) {
        int v = (t >= off) ? sh[t - off] : 0;
        __syncthreads();
        sh[t] += v;
        __syncthreads();
    }
    int ex = sh[t] - mysum;
    if (base + 0 < NN) rowstart[base + 0] = ex;
    if (base + 1 < NN) rowstart[base + 1] = ex + d0;
    if (base + 2 < NN) rowstart[base + 2] = ex + d0 + d1;
    if (base + 3 < NN) rowstart[base + 3] = ex + d0 + d1 + d2;
    if (t == 255) partial[blockIdx.x] = sh[255];
}

__global__ __launch_bounds__(256) void k_scan_add(
    const int* __restrict__ partial, int* __restrict__ rowstart, int* __restrict__ cursor) {
    __shared__ int off;
    int t = threadIdx.x, bI = blockIdx.x;
    if (t == 0) {
        int s = 0;
        for (int k = 0; k < bI; ++k) s += partial[k];
        off = s;
    }
    __syncthreads();
    int base = bI * SCAN_E + t * 4;
#pragma unroll
    for (int i = 0; i < 4; ++i) {
        int idx = base + i;
        if (idx < NN) {
            int v = rowstart[idx] + off;
            rowstart[idx] = v;
            cursor[idx] = v;
        }
    }
    if (bI == 0 && t == 0) rowstart[NN] = NE;
}

__global__ __launch_bounds__(256) void k_scatter(
    const int* __restrict__ ei, const float* __restrict__ ea,
    int* __restrict__ cursor, int2* __restrict__ cpack) {
    int e = blockIdx.x * 256 + threadIdx.x;
    if (e >= NE) return;
    int d = ei[NE + e];
    int p = atomicAdd(&cursor[d], 1);
    cpack[p] = make_int2(ei[e], __float_as_int(ea[e]));
}

// ---------- fused per-node GATv2 layers ----------

// layer 1: wave per node; 2 edges in flight (32 lanes x 4ch = 128ch each);
// head = (lane&31)>>3 (8 lanes x 4ch = 32ch per head)
__global__ __launch_bounds__(256) void k_fused1(
    const int* __restrict__ rs, const int2* __restrict__ cpack,
    const float* __restrict__ xl, const float* __restrict__ xr,
    const float* __restrict__ We, const float* __restrict__ att,
    const float* __restrict__ bias, const float* __restrict__ g,
    const float* __restrict__ b, float* __restrict__ h1) {
    int lane = threadIdx.x & 63;
    int n = blockIdx.x * 4 + (threadIdx.x >> 6);
    if (n >= NN) return;
    int half = lane >> 5;          // which edge of the pair
    int l = lane & 31;
    int c0 = l * 4;                // 4 channels per lane
    float4 xld = *(const float4*)&xl[(size_t)n * 128 + c0];
    float4 We4 = *(const float4*)&We[c0];
    float4 at4 = *(const float4*)&att[c0];
    int beg = rs[n], end = rs[n + 1];
    float4 acc = make_float4(0.f, 0.f, 0.f, 0.f);
    float den = 0.f;
#pragma unroll 2
    for (int p0 = beg; p0 < end; p0 += 2) {
        int p = p0 + half;
        bool valid = p < end;
        int2 pk = cpack[valid ? p : end - 1];
        float eav = __int_as_float(pk.y);
        float4 xrv = *(const float4*)&xr[(size_t)pk.x * 128 + c0];
        float v0 = lrelu(xld.x + xrv.x + eav * We4.x);
        float v1 = lrelu(xld.y + xrv.y + eav * We4.y);
        float v2 = lrelu(xld.z + xrv.z + eav * We4.z);
        float v3 = lrelu(xld.w + xrv.w + eav * We4.w);
        float dot = fmaf(v0, at4.x, fmaf(v1, at4.y, fmaf(v2, at4.z, v3 * at4.w)));
        dot += __shfl_xor(dot, 1);
        dot += __shfl_xor(dot, 2);
        dot += __shfl_xor(dot, 4);         // head logit (8-lane group)
        float el = valid ? __expf(dot) : 0.f;   // max-shift skipped: alpha invariant, |logit| small
        den += el;
        acc.x = fmaf(el, xrv.x, acc.x);
        acc.y = fmaf(el, xrv.y, acc.y);
        acc.z = fmaf(el, xrv.z, acc.z);
        acc.w = fmaf(el, xrv.w, acc.w);
    }
    // combine the two edge-halves
    acc.x += __shfl_xor(acc.x, 32);
    acc.y += __shfl_xor(acc.y, 32);
    acc.z += __shfl_xor(acc.z, 32);
    acc.w += __shfl_xor(acc.w, 32);
    den += __shfl_xor(den, 32);            // per-head denominator (replicated in head group)
    float inv = den > 0.f ? 1.f / den : 0.f;
    float4 bv = *(const float4*)&bias[c0];
    float a0 = acc.x * inv + bv.x;
    float a1 = acc.y * inv + bv.y;
    float a2 = acc.z * inv + bv.z;
    float a3 = acc.w * inv + bv.w;
    float mu = red32g(a0 + a1 + a2 + a3) * (1.f / 128.f);
    float d0 = a0 - mu, d1 = a1 - mu, d2 = a2 - mu, d3 = a3 - mu;
    float var = red32g(d0 * d0 + d1 * d1 + d2 * d2 + d3 * d3) * (1.f / 128.f);
    float rsq = rsqrtf(var + LNEPS);
    float4 gv = *(const float4*)&g[c0];
    float4 bb = *(const float4*)&b[c0];
    float o0 = d0 * rsq * gv.x + bb.x;
    float o1 = d1 * rsq * gv.y + bb.y;
    float o2 = d2 * rsq * gv.z + bb.z;
    float o3 = d3 * rsq * gv.w + bb.w;
    o0 = o0 > 0.f ? o0 : __expf(o0) - 1.f;
    o1 = o1 > 0.f ? o1 : __expf(o1) - 1.f;
    o2 = o2 > 0.f ? o2 : __expf(o2) - 1.f;
    o3 = o3 > 0.f ? o3 : __expf(o3) - 1.f;
    if (half == 0)
        *(float4*)&h1[(size_t)n * 128 + c0] = make_float4(o0, o1, o2, o3);
}

// layer 2: wave per node; 4 edges in flight (16 lanes x 4ch = 64ch each); single head
__global__ __launch_bounds__(256) void k_fused2(
    const int* __restrict__ rs, const int2* __restrict__ cpack,
    const float* __restrict__ xl2, const float* __restrict__ xr2,
    const float* __restrict__ We, const float* __restrict__ att,
    const float* __restrict__ bias, const float* __restrict__ g,
    const float* __restrict__ b, float* __restrict__ out) {
    int lane = threadIdx.x & 63;
    int n = blockIdx.x * 4 + (threadIdx.x >> 6);
    if (n >= NN) return;
    int grp = lane >> 4;           // which edge of the quad
    int l = lane & 15;
    int c0 = l * 4;
    float4 xld = *(const float4*)&xl2[(size_t)n * 64 + c0];
    float4 We4 = *(const float4*)&We[c0];
    float4 at4 = *(const float4*)&att[c0];
    int beg = rs[n], end = rs[n + 1];
    float4 acc = make_float4(0.f, 0.f, 0.f, 0.f);
    float den = 0.f;
    for (int p0 = beg; p0 < end; p0 += 4) {
        int p = p0 + grp;
        bool valid = p < end;
        int2 pk = cpack[valid ? p : end - 1];
        float eav = __int_as_float(pk.y);
        float4 xrv = *(const float4*)&xr2[(size_t)pk.x * 64 + c0];
        float v0 = lrelu(xld.x + xrv.x + eav * We4.x);
        float v1 = lrelu(xld.y + xrv.y + eav * We4.y);
        float v2 = lrelu(xld.z + xrv.z + eav * We4.z);
        float v3 = lrelu(xld.w + xrv.w + eav * We4.w);
        float dot = fmaf(v0, at4.x, fmaf(v1, at4.y, fmaf(v2, at4.z, v3 * at4.w)));
        dot += __shfl_xor(dot, 1);
        dot += __shfl_xor(dot, 2);
        dot += __shfl_xor(dot, 4);
        dot += __shfl_xor(dot, 8);          // logit (16-lane group)
        float el = valid ? __expf(dot) : 0.f;
        den += el;
        acc.x = fmaf(el, xrv.x, acc.x);
        acc.y = fmaf(el, xrv.y, acc.y);
        acc.z = fmaf(el, xrv.z, acc.z);
        acc.w = fmaf(el, xrv.w, acc.w);
    }
    // combine the four edge-groups
    acc.x += __shfl_xor(acc.x, 16); acc.x += __shfl_xor(acc.x, 32);
    acc.y += __shfl_xor(acc.y, 16); acc.y += __shfl_xor(acc.y, 32);
    acc.z += __shfl_xor(acc.z, 16); acc.z += __shfl_xor(acc.z, 32);
    acc.w += __shfl_xor(acc.w, 16); acc.w += __shfl_xor(acc.w, 32);
    den += __shfl_xor(den, 16); den += __shfl_xor(den, 32);
    float inv = den > 0.f ? 1.f / den : 0.f;
    float4 bv = *(const float4*)&bias[c0];
    float a0 = acc.x * inv + bv.x;
    float a1 = acc.y * inv + bv.y;
    float a2 = acc.z * inv + bv.z;
    float a3 = acc.w * inv + bv.w;
    float mu = red16g(a0 + a1 + a2 + a3) * (1.f / 64.f);
    float d0 = a0 - mu, d1 = a1 - mu, d2 = a2 - mu, d3 = a3 - mu;
    float var = red16g(d0 * d0 + d1 * d1 + d2 * d2 + d3 * d3) * (1.f / 64.f);
    float rsq = rsqrtf(var + LNEPS);
    float4 gv = *(const float4*)&g[c0];
    float4 bb = *(const float4*)&b[c0];
    float o0 = d0 * rsq * gv.x + bb.x;
    float o1 = d1 * rsq * gv.y + bb.y;
    float o2 = d2 * rsq * gv.z + bb.z;
    float o3 = d3 * rsq * gv.w + bb.w;
    o0 = o0 > 0.f ? o0 : __expf(o0) - 1.f;
    o1 = o1 > 0.f ? o1 : __expf(o1) - 1.f;
    o2 = o2 > 0.f ? o2 : __expf(o2) - 1.f;
    o3 = o3 > 0.f ? o3 : __expf(o3) - 1.f;
    if (grp == 0)
        *(float4*)&out[(size_t)n * 64 + c0] = make_float4(o0, o1, o2, o3);
}

extern "C" void kernel_launch(void* const* d_in, const int* in_sizes, int n_in,
                              void* d_out, int out_size, void* d_ws, size_t ws_size,
                              hipStream_t stream) {
    const float* x    = (const float*)d_in[0];
    const float* ea   = (const float*)d_in[1];
    const float* W1l  = (const float*)d_in[2];
    const float* W1r  = (const float*)d_in[3];
    const float* W1e  = (const float*)d_in[4];
    const float* att1 = (const float*)d_in[5];
    const float* b1   = (const float*)d_in[6];
    const float* ln1g = (const float*)d_in[7];
    const float* ln1b = (const float*)d_in[8];
    const float* W2l  = (const float*)d_in[9];
    const float* W2r  = (const float*)d_in[10];
    const float* W2e  = (const float*)d_in[11];
    const float* att2 = (const float*)d_in[12];
    const float* b2   = (const float*)d_in[13];
    const float* ln2g = (const float*)d_in[14];
    const float* ln2b = (const float*)d_in[15];
    const int*   ei   = (const int*)d_in[16];
    float* out = (float*)d_out;
    float* ws  = (float*)d_ws;

    const size_t A = (size_t)NN * 128;
    float* xl1 = ws;                       // N*128
    float* xr1 = ws + A;                   // N*128
    float* h1  = ws + 2 * A;               // N*128
    float* xl2 = ws + 3 * A;               // N*64
    float* xr2 = xl2 + (size_t)NN * 64;    // N*64
    int2* cpack  = (int2*)(xr2 + (size_t)NN * 64);   // NE int2 (8B aligned: even float offset)
    int* deg     = (int*)(cpack + (size_t)NE);       // NN
    int* rowstart= deg + NN;                         // NN+1
    int* cursor  = rowstart + NN + 1;                // NN
    int* partial = cursor + NN;                      // NB

    hipMemsetAsync(deg, 0, NN * sizeof(int), stream);

    k_proj1<<<NN / 2, 256, 0, stream>>>(x, W1l, W1r, xl1, xr1);
    k_deg<<<(NE + 255) / 256, 256, 0, stream>>>(ei, deg);
    k_scan_block<<<NB, 256, 0, stream>>>(deg, rowstart, partial);
    k_scan_add<<<NB, 256, 0, stream>>>(partial, rowstart, cursor);
    k_scatter<<<(NE + 255) / 256, 256, 0, stream>>>(ei, ea, cursor, cpack);

    k_fused1<<<(NN + 3) / 4, 256, 0, stream>>>(rowstart, cpack, xl1, xr1,
                                               W1e, att1, b1, ln1g, ln1b, h1);
    k_proj2<<<(NN + 3) / 4, 256, 0, stream>>>(h1, W2l, W2r, xl2, xr2);
    k_fused2<<<(NN + 3) / 4, 256, 0, stream>>>(rowstart, cpack, xl2, xr2,
                                               W2e, att2, b2, ln2g, ln2b, out);
}

// Round 4
// 354.657 us; speedup vs baseline: 3.3459x; 1.1806x over previous
//
#include <hip/hip_runtime.h>
#include <math.h>

#define NN 50000
#define NE 800000
#define IN_CH 10
#define NEGS 0.2f
#define LNEPS 1e-5f
#define SCAN_E 1024   // elements per scan block
#define NB 49         // ceil(NN / SCAN_E)

__device__ __forceinline__ float red16g(float v) {   // sum within aligned 16-lane group
    v += __shfl_xor(v, 1);  v += __shfl_xor(v, 2);
    v += __shfl_xor(v, 4);  v += __shfl_xor(v, 8);
    return v;
}
__device__ __forceinline__ float red32g(float v) {   // sum within aligned 32-lane group
    v = red16g(v); v += __shfl_xor(v, 16);
    return v;
}
__device__ __forceinline__ float lrelu(float v) { return v > 0.f ? v : NEGS * v; }

// ---------- projections ----------

// xl = x @ W1l, xr = x @ W1r   [N,128]; block=256 -> 2 nodes x 128 lanes
__global__ __launch_bounds__(256) void k_proj1(
    const float* __restrict__ x, const float* __restrict__ Wl,
    const float* __restrict__ Wr, float* __restrict__ xl, float* __restrict__ xr) {
    int j = threadIdx.x & 127;
    int n = blockIdx.x * 2 + (threadIdx.x >> 7);
    if (n >= NN) return;
    float al = 0.f, ar = 0.f;
#pragma unroll
    for (int k = 0; k < IN_CH; ++k) {
        float xv = x[n * IN_CH + k];
        al = fmaf(xv, Wl[k * 128 + j], al);
        ar = fmaf(xv, Wr[k * 128 + j], ar);
    }
    xl[n * 128 + j] = al;
    xr[n * 128 + j] = ar;
}

// xl2|xr2 = h1 @ [W2l | W2r]  — LDS-tiled register-blocked fp32 GEMM.
// Block tile: 64 nodes x 128 cols; K staged in chunks of 32.
// Thread (cg = t&15, ng = t>>4): 4 nodes (ng + j*16, adjacent rows within a wave
// for bank-conflict-free b128) x 8 cols (cg*8..+7). 128 FMA per 12 ds_read_b128.
__global__ __launch_bounds__(256) void k_proj2(
    const float* __restrict__ h1, const float* __restrict__ Wl,
    const float* __restrict__ Wr, float* __restrict__ xl2, float* __restrict__ xr2) {
    __shared__ float sh_h[64][36];    // +4 pad: rows 16B-aligned, adjacent rows 4 banks apart
    __shared__ float sh_w[32][128];
    int t = threadIdx.x;
    int cg = t & 15, ng = t >> 4;
    int c0 = cg * 8;
    int nb = blockIdx.x * 64;
    float acc[4][8];
#pragma unroll
    for (int j = 0; j < 4; ++j)
#pragma unroll
        for (int i = 0; i < 8; ++i) acc[j][i] = 0.f;

    for (int kc = 0; kc < 128; kc += 32) {
        // stage h tile: 64 nodes x 32 k
#pragma unroll
        for (int i = 0; i < 2; ++i) {
            int fi = t + i * 256;
            int nl = fi >> 3, kq = fi & 7;
            int n = nb + nl;
            float4 v = make_float4(0.f, 0.f, 0.f, 0.f);
            if (n < NN) v = *(const float4*)&h1[(size_t)n * 128 + kc + kq * 4];
            *(float4*)&sh_h[nl][kq * 4] = v;
        }
        // stage w tile: 32 k x 128 cols (0-63 Wl, 64-127 Wr)
#pragma unroll
        for (int i = 0; i < 4; ++i) {
            int fi = t + i * 256;
            int kl = fi >> 5, col = (fi & 31) * 4;
            const float* src = (col < 64) ? &Wl[(size_t)(kc + kl) * 64 + col]
                                          : &Wr[(size_t)(kc + kl) * 64 + col - 64];
            *(float4*)&sh_w[kl][col] = *(const float4*)src;
        }
        __syncthreads();
#pragma unroll
        for (int kl = 0; kl < 32; kl += 4) {
            float4 hv[4];
#pragma unroll
            for (int j = 0; j < 4; ++j) hv[j] = *(const float4*)&sh_h[ng + j * 16][kl];
#pragma unroll
            for (int kk = 0; kk < 4; ++kk) {
                float4 wa = *(const float4*)&sh_w[kl + kk][c0];
                float4 wb = *(const float4*)&sh_w[kl + kk][c0 + 4];
#pragma unroll
                for (int j = 0; j < 4; ++j) {
                    float hs = kk == 0 ? hv[j].x : kk == 1 ? hv[j].y : kk == 2 ? hv[j].z : hv[j].w;
                    acc[j][0] = fmaf(hs, wa.x, acc[j][0]);
                    acc[j][1] = fmaf(hs, wa.y, acc[j][1]);
                    acc[j][2] = fmaf(hs, wa.z, acc[j][2]);
                    acc[j][3] = fmaf(hs, wa.w, acc[j][3]);
                    acc[j][4] = fmaf(hs, wb.x, acc[j][4]);
                    acc[j][5] = fmaf(hs, wb.y, acc[j][5]);
                    acc[j][6] = fmaf(hs, wb.z, acc[j][6]);
                    acc[j][7] = fmaf(hs, wb.w, acc[j][7]);
                }
            }
        }
        __syncthreads();
    }
    float* dst = (cg < 8) ? xl2 : xr2;
    int cc = (cg < 8) ? c0 : c0 - 64;
#pragma unroll
    for (int j = 0; j < 4; ++j) {
        int n = nb + ng + j * 16;
        if (n < NN) {
            *(float4*)&dst[(size_t)n * 64 + cc] =
                make_float4(acc[j][0], acc[j][1], acc[j][2], acc[j][3]);
            *(float4*)&dst[(size_t)n * 64 + cc + 4] =
                make_float4(acc[j][4], acc[j][5], acc[j][6], acc[j][7]);
        }
    }
}

// ---------- CSR build (edges grouped by dst; payload packed as {src, ea}) ----------

__global__ __launch_bounds__(256) void k_deg(const int* __restrict__ ei, int* __restrict__ deg) {
    int e = blockIdx.x * 256 + threadIdx.x;
    if (e < NE) atomicAdd(&deg[ei[NE + e]], 1);
}

__global__ __launch_bounds__(256) void k_scan_block(
    const int* __restrict__ deg, int* __restrict__ rowstart, int* __restrict__ partial) {
    __shared__ int sh[256];
    int t = threadIdx.x;
    int base = blockIdx.x * SCAN_E + t * 4;
    int d0 = 0, d1 = 0, d2 = 0, d3 = 0;
    if (base + 0 < NN) d0 = deg[base + 0];
    if (base + 1 < NN) d1 = deg[base + 1];
    if (base + 2 < NN) d2 = deg[base + 2];
    if (base + 3 < NN) d3 = deg[base + 3];
    int mysum = d0 + d1 + d2 + d3;
    sh[t] = mysum;
    __syncthreads();
    for (int off = 1; off < 256; off <<= 1) {
        int v = (t >= off) ? sh[t - off] : 0;
        __syncthreads();
        sh[t] += v;
        __syncthreads();
    }
    int ex = sh[t] - mysum;
    if (base + 0 < NN) rowstart[base + 0] = ex;
    if (base + 1 < NN) rowstart[base + 1] = ex + d0;
    if (base + 2 < NN) rowstart[base + 2] = ex + d0 + d1;
    if (base + 3 < NN) rowstart[base + 3] = ex + d0 + d1 + d2;
    if (t == 255) partial[blockIdx.x] = sh[255];
}

__global__ __launch_bounds__(256) void k_scan_add(
    const int* __restrict__ partial, int* __restrict__ rowstart, int* __restrict__ cursor) {
    __shared__ int off;
    int t = threadIdx.x, bI = blockIdx.x;
    if (t == 0) {
        int s = 0;
        for (int k = 0; k < bI; ++k) s += partial[k];
        off = s;
    }
    __syncthreads();
    int base = bI * SCAN_E + t * 4;
#pragma unroll
    for (int i = 0; i < 4; ++i) {
        int idx = base + i;
        if (idx < NN) {
            int v = rowstart[idx] + off;
            rowstart[idx] = v;
            cursor[idx] = v;
        }
    }
    if (bI == 0 && t == 0) rowstart[NN] = NE;
}

__global__ __launch_bounds__(256) void k_scatter(
    const int* __restrict__ ei, const float* __restrict__ ea,
    int* __restrict__ cursor, int2* __restrict__ cpack) {
    int e = blockIdx.x * 256 + threadIdx.x;
    if (e >= NE) return;
    int d = ei[NE + e];
    int p = atomicAdd(&cursor[d], 1);
    cpack[p] = make_int2(ei[e], __float_as_int(ea[e]));
}

// ---------- fused per-node GATv2 layers ----------

// layer 1: wave per node; 2 edge slots x 2 halves = 4 gathers in flight.
// 32 lanes x 4ch = 128ch per edge; head = (lane&31)>>3.
__global__ __launch_bounds__(256) void k_fused1(
    const int* __restrict__ rs, const int2* __restrict__ cpack,
    const float* __restrict__ xl, const float* __restrict__ xr,
    const float* __restrict__ We, const float* __restrict__ att,
    const float* __restrict__ bias, const float* __restrict__ g,
    const float* __restrict__ b, float* __restrict__ h1) {
    int lane = threadIdx.x & 63;
    int n = blockIdx.x * 4 + (threadIdx.x >> 6);
    if (n >= NN) return;
    int half = lane >> 5;
    int l = lane & 31;
    int c0 = l * 4;
    float4 xld = *(const float4*)&xl[(size_t)n * 128 + c0];
    float4 We4 = *(const float4*)&We[c0];
    float4 at4 = *(const float4*)&att[c0];
    int beg = rs[n], end = rs[n + 1];
    float4 accA = make_float4(0.f, 0.f, 0.f, 0.f);
    float4 accB = make_float4(0.f, 0.f, 0.f, 0.f);
    float denA = 0.f, denB = 0.f;
    for (int p0 = beg; p0 < end; p0 += 4) {
        int pA = p0 + half;
        int pB = p0 + 2 + half;
        bool vA = pA < end, vB = pB < end;
        int2 ka = cpack[vA ? pA : end - 1];
        int2 kb = cpack[vB ? pB : end - 1];
        float eaA = __int_as_float(ka.y);
        float eaB = __int_as_float(kb.y);
        float4 xa = *(const float4*)&xr[(size_t)ka.x * 128 + c0];
        float4 xb = *(const float4*)&xr[(size_t)kb.x * 128 + c0];
        float a0 = lrelu(xld.x + xa.x + eaA * We4.x);
        float a1 = lrelu(xld.y + xa.y + eaA * We4.y);
        float a2 = lrelu(xld.z + xa.z + eaA * We4.z);
        float a3 = lrelu(xld.w + xa.w + eaA * We4.w);
        float b0 = lrelu(xld.x + xb.x + eaB * We4.x);
        float b1 = lrelu(xld.y + xb.y + eaB * We4.y);
        float b2 = lrelu(xld.z + xb.z + eaB * We4.z);
        float b3 = lrelu(xld.w + xb.w + eaB * We4.w);
        float dA = fmaf(a0, at4.x, fmaf(a1, at4.y, fmaf(a2, at4.z, a3 * at4.w)));
        float dB = fmaf(b0, at4.x, fmaf(b1, at4.y, fmaf(b2, at4.z, b3 * at4.w)));
        dA += __shfl_xor(dA, 1); dB += __shfl_xor(dB, 1);
        dA += __shfl_xor(dA, 2); dB += __shfl_xor(dB, 2);
        dA += __shfl_xor(dA, 4); dB += __shfl_xor(dB, 4);   // head logits
        float elA = vA ? __expf(dA) : 0.f;   // max-shift skipped: alpha invariant, |logit| small
        float elB = vB ? __expf(dB) : 0.f;
        denA += elA; denB += elB;
        accA.x = fmaf(elA, xa.x, accA.x); accB.x = fmaf(elB, xb.x, accB.x);
        accA.y = fmaf(elA, xa.y, accA.y); accB.y = fmaf(elB, xb.y, accB.y);
        accA.z = fmaf(elA, xa.z, accA.z); accB.z = fmaf(elB, xb.z, accB.z);
        accA.w = fmaf(elA, xa.w, accA.w); accB.w = fmaf(elB, xb.w, accB.w);
    }
    float4 acc = make_float4(accA.x + accB.x, accA.y + accB.y,
                             accA.z + accB.z, accA.w + accB.w);
    float den = denA + denB;
    acc.x += __shfl_xor(acc.x, 32);
    acc.y += __shfl_xor(acc.y, 32);
    acc.z += __shfl_xor(acc.z, 32);
    acc.w += __shfl_xor(acc.w, 32);
    den += __shfl_xor(den, 32);
    float inv = den > 0.f ? 1.f / den : 0.f;
    float4 bv = *(const float4*)&bias[c0];
    float a0 = acc.x * inv + bv.x;
    float a1 = acc.y * inv + bv.y;
    float a2 = acc.z * inv + bv.z;
    float a3 = acc.w * inv + bv.w;
    float mu = red32g(a0 + a1 + a2 + a3) * (1.f / 128.f);
    float d0 = a0 - mu, d1 = a1 - mu, d2 = a2 - mu, d3 = a3 - mu;
    float var = red32g(d0 * d0 + d1 * d1 + d2 * d2 + d3 * d3) * (1.f / 128.f);
    float rsq = rsqrtf(var + LNEPS);
    float4 gv = *(const float4*)&g[c0];
    float4 bb = *(const float4*)&b[c0];
    float o0 = d0 * rsq * gv.x + bb.x;
    float o1 = d1 * rsq * gv.y + bb.y;
    float o2 = d2 * rsq * gv.z + bb.z;
    float o3 = d3 * rsq * gv.w + bb.w;
    o0 = o0 > 0.f ? o0 : __expf(o0) - 1.f;
    o1 = o1 > 0.f ? o1 : __expf(o1) - 1.f;
    o2 = o2 > 0.f ? o2 : __expf(o2) - 1.f;
    o3 = o3 > 0.f ? o3 : __expf(o3) - 1.f;
    if (half == 0)
        *(float4*)&h1[(size_t)n * 128 + c0] = make_float4(o0, o1, o2, o3);
}

// layer 2: wave per node; 4 edge groups x 2 slots = 8 gathers in flight; single head
__global__ __launch_bounds__(256) void k_fused2(
    const int* __restrict__ rs, const int2* __restrict__ cpack,
    const float* __restrict__ xl2, const float* __restrict__ xr2,
    const float* __restrict__ We, const float* __restrict__ att,
    const float* __restrict__ bias, const float* __restrict__ g,
    const float* __restrict__ b, float* __restrict__ out) {
    int lane = threadIdx.x & 63;
    int n = blockIdx.x * 4 + (threadIdx.x >> 6);
    if (n >= NN) return;
    int grp = lane >> 4;
    int l = lane & 15;
    int c0 = l * 4;
    float4 xld = *(const float4*)&xl2[(size_t)n * 64 + c0];
    float4 We4 = *(const float4*)&We[c0];
    float4 at4 = *(const float4*)&att[c0];
    int beg = rs[n], end = rs[n + 1];
    float4 accA = make_float4(0.f, 0.f, 0.f, 0.f);
    float4 accB = make_float4(0.f, 0.f, 0.f, 0.f);
    float denA = 0.f, denB = 0.f;
    for (int p0 = beg; p0 < end; p0 += 8) {
        int pA = p0 + grp;
        int pB = p0 + 4 + grp;
        bool vA = pA < end, vB = pB < end;
        int2 ka = cpack[vA ? pA : end - 1];
        int2 kb = cpack[vB ? pB : end - 1];
        float eaA = __int_as_float(ka.y);
        float eaB = __int_as_float(kb.y);
        float4 xa = *(const float4*)&xr2[(size_t)ka.x * 64 + c0];
        float4 xb = *(const float4*)&xr2[(size_t)kb.x * 64 + c0];
        float a0 = lrelu(xld.x + xa.x + eaA * We4.x);
        float a1 = lrelu(xld.y + xa.y + eaA * We4.y);
        float a2 = lrelu(xld.z + xa.z + eaA * We4.z);
        float a3 = lrelu(xld.w + xa.w + eaA * We4.w);
        float b0 = lrelu(xld.x + xb.x + eaB * We4.x);
        float b1 = lrelu(xld.y + xb.y + eaB * We4.y);
        float b2 = lrelu(xld.z + xb.z + eaB * We4.z);
        float b3 = lrelu(xld.w + xb.w + eaB * We4.w);
        float dA = fmaf(a0, at4.x, fmaf(a1, at4.y, fmaf(a2, at4.z, a3 * at4.w)));
        float dB = fmaf(b0, at4.x, fmaf(b1, at4.y, fmaf(b2, at4.z, b3 * at4.w)));
        dA += __shfl_xor(dA, 1); dB += __shfl_xor(dB, 1);
        dA += __shfl_xor(dA, 2); dB += __shfl_xor(dB, 2);
        dA += __shfl_xor(dA, 4); dB += __shfl_xor(dB, 4);
        dA += __shfl_xor(dA, 8); dB += __shfl_xor(dB, 8);
        float elA = vA ? __expf(dA) : 0.f;
        float elB = vB ? __expf(dB) : 0.f;
        denA += elA; denB += elB;
        accA.x = fmaf(elA, xa.x, accA.x); accB.x = fmaf(elB, xb.x, accB.x);
        accA.y = fmaf(elA, xa.y, accA.y); accB.y = fmaf(elB, xb.y, accB.y);
        accA.z = fmaf(elA, xa.z, accA.z); accB.z = fmaf(elB, xb.z, accB.z);
        accA.w = fmaf(elA, xa.w, accA.w); accB.w = fmaf(elB, xb.w, accB.w);
    }
    float4 acc = make_float4(accA.x + accB.x, accA.y + accB.y,
                             accA.z + accB.z, accA.w + accB.w);
    float den = denA + denB;
    acc.x += __shfl_xor(acc.x, 16); acc.x += __shfl_xor(acc.x, 32);
    acc.y += __shfl_xor(acc.y, 16); acc.y += __shfl_xor(acc.y, 32);
    acc.z += __shfl_xor(acc.z, 16); acc.z += __shfl_xor(acc.z, 32);
    acc.w += __shfl_xor(acc.w, 16); acc.w += __shfl_xor(acc.w, 32);
    den += __shfl_xor(den, 16); den += __shfl_xor(den, 32);
    float inv = den > 0.f ? 1.f / den : 0.f;
    float4 bv = *(const float4*)&bias[c0];
    float a0 = acc.x * inv + bv.x;
    float a1 = acc.y * inv + bv.y;
    float a2 = acc.z * inv + bv.z;
    float a3 = acc.w * inv + bv.w;
    float mu = red16g(a0 + a1 + a2 + a3) * (1.f / 64.f);
    float d0 = a0 - mu, d1 = a1 - mu, d2 = a2 - mu, d3 = a3 - mu;
    float var = red16g(d0 * d0 + d1 * d1 + d2 * d2 + d3 * d3) * (1.f / 64.f);
    float rsq = rsqrtf(var + LNEPS);
    float4 gv = *(const float4*)&g[c0];
    float4 bb = *(const float4*)&b[c0];
    float o0 = d0 * rsq * gv.x + bb.x;
    float o1 = d1 * rsq * gv.y + bb.y;
    float o2 = d2 * rsq * gv.z + bb.z;
    float o3 = d3 * rsq * gv.w + bb.w;
    o0 = o0 > 0.f ? o0 : __expf(o0) - 1.f;
    o1 = o1 > 0.f ? o1 : __expf(o1) - 1.f;
    o2 = o2 > 0.f ? o2 : __expf(o2) - 1.f;
    o3 = o3 > 0.f ? o3 : __expf(o3) - 1.f;
    if (grp == 0)
        *(float4*)&out[(size_t)n * 64 + c0] = make_float4(o0, o1, o2, o3);
}

extern "C" void kernel_launch(void* const* d_in, const int* in_sizes, int n_in,
                              void* d_out, int out_size, void* d_ws, size_t ws_size,
                              hipStream_t stream) {
    const float* x    = (const float*)d_in[0];
    const float* ea   = (const float*)d_in[1];
    const float* W1l  = (const float*)d_in[2];
    const float* W1r  = (const float*)d_in[3];
    const float* W1e  = (const float*)d_in[4];
    const float* att1 = (const float*)d_in[5];
    const float* b1   = (const float*)d_in[6];
    const float* ln1g = (const float*)d_in[7];
    const float* ln1b = (const float*)d_in[8];
    const float* W2l  = (const float*)d_in[9];
    const float* W2r  = (const float*)d_in[10];
    const float* W2e  = (const float*)d_in[11];
    const float* att2 = (const float*)d_in[12];
    const float* b2   = (const float*)d_in[13];
    const float* ln2g = (const float*)d_in[14];
    const float* ln2b = (const float*)d_in[15];
    const int*   ei   = (const int*)d_in[16];
    float* out = (float*)d_out;
    float* ws  = (float*)d_ws;

    const size_t A = (size_t)NN * 128;
    float* xl1 = ws;                       // N*128
    float* xr1 = ws + A;                   // N*128
    float* h1  = ws + 2 * A;               // N*128
    float* xl2 = ws + 3 * A;               // N*64
    float* xr2 = xl2 + (size_t)NN * 64;    // N*64
    int2* cpack  = (int2*)(xr2 + (size_t)NN * 64);   // NE int2
    int* deg     = (int*)(cpack + (size_t)NE);       // NN
    int* rowstart= deg + NN;                         // NN+1
    int* cursor  = rowstart + NN + 1;                // NN
    int* partial = cursor + NN;                      // NB

    hipMemsetAsync(deg, 0, NN * sizeof(int), stream);

    k_proj1<<<NN / 2, 256, 0, stream>>>(x, W1l, W1r, xl1, xr1);
    k_deg<<<(NE + 255) / 256, 256, 0, stream>>>(ei, deg);
    k_scan_block<<<NB, 256, 0, stream>>>(deg, rowstart, partial);
    k_scan_add<<<NB, 256, 0, stream>>>(partial, rowstart, cursor);
    k_scatter<<<(NE + 255) / 256, 256, 0, stream>>>(ei, ea, cursor, cpack);

    k_fused1<<<(NN + 3) / 4, 256, 0, stream>>>(rowstart, cpack, xl1, xr1,
                                               W1e, att1, b1, ln1g, ln1b, h1);
    k_proj2<<<(NN + 63) / 64, 256, 0, stream>>>(h1, W2l, W2r, xl2, xr2);
    k_fused2<<<(NN + 3) / 4, 256, 0, stream>>>(rowstart, cpack, xl2, xr2,
                                               W2e, att2, b2, ln2g, ln2b, out);
}

// Round 5
// 349.819 us; speedup vs baseline: 3.3922x; 1.0138x over previous
//
#include <hip/hip_runtime.h>
#include <math.h>

#define NN 50000
#define NE 800000
#define IN_CH 10
#define NEGS 0.2f
#define LNEPS 1e-5f
#define SCAN_E 1024   // elements per scan block
#define NB 49         // ceil(NN / SCAN_E)

__device__ __forceinline__ float red16g(float v) {   // sum within aligned 16-lane group
    v += __shfl_xor(v, 1);  v += __shfl_xor(v, 2);
    v += __shfl_xor(v, 4);  v += __shfl_xor(v, 8);
    return v;
}
__device__ __forceinline__ float red32g(float v) {   // sum within aligned 32-lane group
    v = red16g(v); v += __shfl_xor(v, 16);
    return v;
}
__device__ __forceinline__ float lrelu(float v) { return v > 0.f ? v : NEGS * v; }

// bf16 pack/unpack: RTNE encode, 1-op decode (bf16 pair per dword)
__device__ __forceinline__ unsigned pack_bf16(float a, float b) {
    unsigned ua = __float_as_uint(a);
    unsigned ub = __float_as_uint(b);
    ua = (ua + 0x7FFFu + ((ua >> 16) & 1u)) >> 16;
    ub = (ub + 0x7FFFu + ((ub >> 16) & 1u)) & 0xFFFF0000u;
    return ua | ub;
}
__device__ __forceinline__ float bf_lo(unsigned d) { return __uint_as_float(d << 16); }
__device__ __forceinline__ float bf_hi(unsigned d) { return __uint_as_float(d & 0xFFFF0000u); }

// ---------- projections ----------

// xl = x @ W1l (f32), xrb = bf16(x @ W1r)  [N,128]; 64 lanes/node, 2 ch/lane
__global__ __launch_bounds__(256) void k_proj1(
    const float* __restrict__ x, const float* __restrict__ Wl,
    const float* __restrict__ Wr, float* __restrict__ xl, unsigned* __restrict__ xrb) {
    int lane = threadIdx.x & 63;
    int n = blockIdx.x * 4 + (threadIdx.x >> 6);
    if (n >= NN) return;
    int c0 = lane * 2;
    float al0 = 0.f, al1 = 0.f, ar0 = 0.f, ar1 = 0.f;
#pragma unroll
    for (int k = 0; k < IN_CH; ++k) {
        float xv = x[n * IN_CH + k];
        al0 = fmaf(xv, Wl[k * 128 + c0], al0);
        al1 = fmaf(xv, Wl[k * 128 + c0 + 1], al1);
        ar0 = fmaf(xv, Wr[k * 128 + c0], ar0);
        ar1 = fmaf(xv, Wr[k * 128 + c0 + 1], ar1);
    }
    *(float2*)&xl[(size_t)n * 128 + c0] = make_float2(al0, al1);
    xrb[(size_t)n * 64 + lane] = pack_bf16(ar0, ar1);
}

// xl2 (f32) | xr2b (bf16) = h1 @ [W2l | W2r]  — LDS-tiled register-blocked fp32 GEMM.
__global__ __launch_bounds__(256) void k_proj2(
    const float* __restrict__ h1, const float* __restrict__ Wl,
    const float* __restrict__ Wr, float* __restrict__ xl2, unsigned* __restrict__ xr2b) {
    __shared__ float sh_h[64][36];    // +4 pad
    __shared__ float sh_w[32][128];
    int t = threadIdx.x;
    int cg = t & 15, ng = t >> 4;
    int c0 = cg * 8;
    int nb = blockIdx.x * 64;
    float acc[4][8];
#pragma unroll
    for (int j = 0; j < 4; ++j)
#pragma unroll
        for (int i = 0; i < 8; ++i) acc[j][i] = 0.f;

    for (int kc = 0; kc < 128; kc += 32) {
#pragma unroll
        for (int i = 0; i < 2; ++i) {
            int fi = t + i * 256;
            int nl = fi >> 3, kq = fi & 7;
            int n = nb + nl;
            float4 v = make_float4(0.f, 0.f, 0.f, 0.f);
            if (n < NN) v = *(const float4*)&h1[(size_t)n * 128 + kc + kq * 4];
            *(float4*)&sh_h[nl][kq * 4] = v;
        }
#pragma unroll
        for (int i = 0; i < 4; ++i) {
            int fi = t + i * 256;
            int kl = fi >> 5, col = (fi & 31) * 4;
            const float* src = (col < 64) ? &Wl[(size_t)(kc + kl) * 64 + col]
                                          : &Wr[(size_t)(kc + kl) * 64 + col - 64];
            *(float4*)&sh_w[kl][col] = *(const float4*)src;
        }
        __syncthreads();
#pragma unroll
        for (int kl = 0; kl < 32; kl += 4) {
            float4 hv[4];
#pragma unroll
            for (int j = 0; j < 4; ++j) hv[j] = *(const float4*)&sh_h[ng + j * 16][kl];
#pragma unroll
            for (int kk = 0; kk < 4; ++kk) {
                float4 wa = *(const float4*)&sh_w[kl + kk][c0];
                float4 wb = *(const float4*)&sh_w[kl + kk][c0 + 4];
#pragma unroll
                for (int j = 0; j < 4; ++j) {
                    float hs = kk == 0 ? hv[j].x : kk == 1 ? hv[j].y : kk == 2 ? hv[j].z : hv[j].w;
                    acc[j][0] = fmaf(hs, wa.x, acc[j][0]);
                    acc[j][1] = fmaf(hs, wa.y, acc[j][1]);
                    acc[j][2] = fmaf(hs, wa.z, acc[j][2]);
                    acc[j][3] = fmaf(hs, wa.w, acc[j][3]);
                    acc[j][4] = fmaf(hs, wb.x, acc[j][4]);
                    acc[j][5] = fmaf(hs, wb.y, acc[j][5]);
                    acc[j][6] = fmaf(hs, wb.z, acc[j][6]);
                    acc[j][7] = fmaf(hs, wb.w, acc[j][7]);
                }
            }
        }
        __syncthreads();
    }
    if (cg < 8) {
#pragma unroll
        for (int j = 0; j < 4; ++j) {
            int n = nb + ng + j * 16;
            if (n < NN) {
                *(float4*)&xl2[(size_t)n * 64 + c0] =
                    make_float4(acc[j][0], acc[j][1], acc[j][2], acc[j][3]);
                *(float4*)&xl2[(size_t)n * 64 + c0 + 4] =
                    make_float4(acc[j][4], acc[j][5], acc[j][6], acc[j][7]);
            }
        }
    } else {
        int cc = c0 - 64;   // 0..56, multiple of 8 -> dword index cc/2 is uint4-aligned
#pragma unroll
        for (int j = 0; j < 4; ++j) {
            int n = nb + ng + j * 16;
            if (n < NN) {
                uint4 pk;
                pk.x = pack_bf16(acc[j][0], acc[j][1]);
                pk.y = pack_bf16(acc[j][2], acc[j][3]);
                pk.z = pack_bf16(acc[j][4], acc[j][5]);
                pk.w = pack_bf16(acc[j][6], acc[j][7]);
                *(uint4*)&xr2b[(size_t)n * 32 + (cc >> 1)] = pk;
            }
        }
    }
}

// ---------- CSR build (edges grouped by dst; payload packed as {src, ea}) ----------

__global__ __launch_bounds__(256) void k_deg(const int* __restrict__ ei, int* __restrict__ deg) {
    int e = blockIdx.x * 256 + threadIdx.x;
    if (e < NE) atomicAdd(&deg[ei[NE + e]], 1);
}

__global__ __launch_bounds__(256) void k_scan_block(
    const int* __restrict__ deg, int* __restrict__ rowstart, int* __restrict__ partial) {
    __shared__ int sh[256];
    int t = threadIdx.x;
    int base = blockIdx.x * SCAN_E + t * 4;
    int d0 = 0, d1 = 0, d2 = 0, d3 = 0;
    if (base + 0 < NN) d0 = deg[base + 0];
    if (base + 1 < NN) d1 = deg[base + 1];
    if (base + 2 < NN) d2 = deg[base + 2];
    if (base + 3 < NN) d3 = deg[base + 3];
    int mysum = d0 + d1 + d2 + d3;
    sh[t] = mysum;
    __syncthreads();
    for (int off = 1; off < 256; off <<= 1) {
        int v = (t >= off) ? sh[t - off] : 0;
        __syncthreads();
        sh[t] += v;
        __syncthreads();
    }
    int ex = sh[t] - mysum;
    if (base + 0 < NN) rowstart[base + 0] = ex;
    if (base + 1 < NN) rowstart[base + 1] = ex + d0;
    if (base + 2 < NN) rowstart[base + 2] = ex + d0 + d1;
    if (base + 3 < NN) rowstart[base + 3] = ex + d0 + d1 + d2;
    if (t == 255) partial[blockIdx.x] = sh[255];
}

__global__ __launch_bounds__(256) void k_scan_add(
    const int* __restrict__ partial, int* __restrict__ rowstart, int* __restrict__ cursor) {
    __shared__ int off;
    int t = threadIdx.x, bI = blockIdx.x;
    if (t == 0) {
        int s = 0;
        for (int k = 0; k < bI; ++k) s += partial[k];
        off = s;
    }
    __syncthreads();
    int base = bI * SCAN_E + t * 4;
#pragma unroll
    for (int i = 0; i < 4; ++i) {
        int idx = base + i;
        if (idx < NN) {
            int v = rowstart[idx] + off;
            rowstart[idx] = v;
            cursor[idx] = v;
        }
    }
    if (bI == 0 && t == 0) rowstart[NN] = NE;
}

__global__ __launch_bounds__(256) void k_scatter(
    const int* __restrict__ ei, const float* __restrict__ ea,
    int* __restrict__ cursor, int2* __restrict__ cpack) {
    int e = blockIdx.x * 256 + threadIdx.x;
    if (e >= NE) return;
    int d = ei[NE + e];
    int p = atomicAdd(&cursor[d], 1);
    cpack[p] = make_int2(ei[e], __float_as_int(ea[e]));
}

// ---------- fused per-node GATv2 layers ----------

// layer 1: wave per node; 4 edge slots x 2 halves = 8 bf16 gathers in flight.
// 32 lanes x 4ch = 128ch per edge; head = (lane&31)>>3.
__global__ __launch_bounds__(256) void k_fused1(
    const int* __restrict__ rs, const int2* __restrict__ cpack,
    const float* __restrict__ xl, const uint2* __restrict__ xrb,
    const float* __restrict__ We, const float* __restrict__ att,
    const float* __restrict__ bias, const float* __restrict__ g,
    const float* __restrict__ b, float* __restrict__ h1) {
    int lane = threadIdx.x & 63;
    int n = blockIdx.x * 4 + (threadIdx.x >> 6);
    if (n >= NN) return;
    int half = lane >> 5;
    int l = lane & 31;
    int c0 = l * 4;
    float4 xld = *(const float4*)&xl[(size_t)n * 128 + c0];
    float4 We4 = *(const float4*)&We[c0];
    float4 at4 = *(const float4*)&att[c0];
    int beg = rs[n], end = rs[n + 1];
    float4 acc[2];
    acc[0] = make_float4(0.f, 0.f, 0.f, 0.f);
    acc[1] = make_float4(0.f, 0.f, 0.f, 0.f);
    float den[2] = {0.f, 0.f};
    for (int p0 = beg; p0 < end; p0 += 8) {
#pragma unroll
        for (int s = 0; s < 4; ++s) {
            int p = p0 + s * 2 + half;
            bool valid = p < end;
            int2 pk = cpack[valid ? p : end - 1];
            float eav = __int_as_float(pk.y);
            uint2 dw = xrb[(size_t)pk.x * 32 + l];
            float x0 = bf_lo(dw.x), x1 = bf_hi(dw.x);
            float x2 = bf_lo(dw.y), x3 = bf_hi(dw.y);
            float v0 = lrelu(fmaf(eav, We4.x, xld.x + x0));
            float v1 = lrelu(fmaf(eav, We4.y, xld.y + x1));
            float v2 = lrelu(fmaf(eav, We4.z, xld.z + x2));
            float v3 = lrelu(fmaf(eav, We4.w, xld.w + x3));
            float dot = fmaf(v0, at4.x, fmaf(v1, at4.y, fmaf(v2, at4.z, v3 * at4.w)));
            dot += __shfl_xor(dot, 1);
            dot += __shfl_xor(dot, 2);
            dot += __shfl_xor(dot, 4);      // head logit (8-lane group)
            float el = valid ? __expf(dot) : 0.f;   // max-shift skipped: alpha invariant
            int w = s & 1;
            den[w] += el;
            acc[w].x = fmaf(el, x0, acc[w].x);
            acc[w].y = fmaf(el, x1, acc[w].y);
            acc[w].z = fmaf(el, x2, acc[w].z);
            acc[w].w = fmaf(el, x3, acc[w].w);
        }
    }
    float4 a4 = make_float4(acc[0].x + acc[1].x, acc[0].y + acc[1].y,
                            acc[0].z + acc[1].z, acc[0].w + acc[1].w);
    float den0 = den[0] + den[1];
    a4.x += __shfl_xor(a4.x, 32);
    a4.y += __shfl_xor(a4.y, 32);
    a4.z += __shfl_xor(a4.z, 32);
    a4.w += __shfl_xor(a4.w, 32);
    den0 += __shfl_xor(den0, 32);
    float inv = den0 > 0.f ? 1.f / den0 : 0.f;
    float4 bv = *(const float4*)&bias[c0];
    float a0 = a4.x * inv + bv.x;
    float a1 = a4.y * inv + bv.y;
    float a2 = a4.z * inv + bv.z;
    float a3 = a4.w * inv + bv.w;
    float mu = red32g(a0 + a1 + a2 + a3) * (1.f / 128.f);
    float d0 = a0 - mu, d1 = a1 - mu, d2 = a2 - mu, d3 = a3 - mu;
    float var = red32g(d0 * d0 + d1 * d1 + d2 * d2 + d3 * d3) * (1.f / 128.f);
    float rsq = rsqrtf(var + LNEPS);
    float4 gv = *(const float4*)&g[c0];
    float4 bb = *(const float4*)&b[c0];
    float o0 = d0 * rsq * gv.x + bb.x;
    float o1 = d1 * rsq * gv.y + bb.y;
    float o2 = d2 * rsq * gv.z + bb.z;
    float o3 = d3 * rsq * gv.w + bb.w;
    o0 = o0 > 0.f ? o0 : __expf(o0) - 1.f;
    o1 = o1 > 0.f ? o1 : __expf(o1) - 1.f;
    o2 = o2 > 0.f ? o2 : __expf(o2) - 1.f;
    o3 = o3 > 0.f ? o3 : __expf(o3) - 1.f;
    if (half == 0)
        *(float4*)&h1[(size_t)n * 128 + c0] = make_float4(o0, o1, o2, o3);
}

// layer 2: wave per node; 4 edge groups x 2 slots = 8 bf16 gathers in flight; single head
__global__ __launch_bounds__(256) void k_fused2(
    const int* __restrict__ rs, const int2* __restrict__ cpack,
    const float* __restrict__ xl2, const uint2* __restrict__ xr2b,
    const float* __restrict__ We, const float* __restrict__ att,
    const float* __restrict__ bias, const float* __restrict__ g,
    const float* __restrict__ b, float* __restrict__ out) {
    int lane = threadIdx.x & 63;
    int n = blockIdx.x * 4 + (threadIdx.x >> 6);
    if (n >= NN) return;
    int grp = lane >> 4;
    int l = lane & 15;
    int c0 = l * 4;
    float4 xld = *(const float4*)&xl2[(size_t)n * 64 + c0];
    float4 We4 = *(const float4*)&We[c0];
    float4 at4 = *(const float4*)&att[c0];
    int beg = rs[n], end = rs[n + 1];
    float4 acc[2];
    acc[0] = make_float4(0.f, 0.f, 0.f, 0.f);
    acc[1] = make_float4(0.f, 0.f, 0.f, 0.f);
    float den[2] = {0.f, 0.f};
    for (int p0 = beg; p0 < end; p0 += 8) {
#pragma unroll
        for (int s = 0; s < 2; ++s) {
            int p = p0 + s * 4 + grp;
            bool valid = p < end;
            int2 pk = cpack[valid ? p : end - 1];
            float eav = __int_as_float(pk.y);
            uint2 dw = xr2b[(size_t)pk.x * 16 + l];
            float x0 = bf_lo(dw.x), x1 = bf_hi(dw.x);
            float x2 = bf_lo(dw.y), x3 = bf_hi(dw.y);
            float v0 = lrelu(fmaf(eav, We4.x, xld.x + x0));
            float v1 = lrelu(fmaf(eav, We4.y, xld.y + x1));
            float v2 = lrelu(fmaf(eav, We4.z, xld.z + x2));
            float v3 = lrelu(fmaf(eav, We4.w, xld.w + x3));
            float dot = fmaf(v0, at4.x, fmaf(v1, at4.y, fmaf(v2, at4.z, v3 * at4.w)));
            dot += __shfl_xor(dot, 1);
            dot += __shfl_xor(dot, 2);
            dot += __shfl_xor(dot, 4);
            dot += __shfl_xor(dot, 8);      // logit (16-lane group)
            float el = valid ? __expf(dot) : 0.f;
            den[s] += el;
            acc[s].x = fmaf(el, x0, acc[s].x);
            acc[s].y = fmaf(el, x1, acc[s].y);
            acc[s].z = fmaf(el, x2, acc[s].z);
            acc[s].w = fmaf(el, x3, acc[s].w);
        }
    }
    float4 a4 = make_float4(acc[0].x + acc[1].x, acc[0].y + acc[1].y,
                            acc[0].z + acc[1].z, acc[0].w + acc[1].w);
    float den0 = den[0] + den[1];
    a4.x += __shfl_xor(a4.x, 16); a4.x += __shfl_xor(a4.x, 32);
    a4.y += __shfl_xor(a4.y, 16); a4.y += __shfl_xor(a4.y, 32);
    a4.z += __shfl_xor(a4.z, 16); a4.z += __shfl_xor(a4.z, 32);
    a4.w += __shfl_xor(a4.w, 16); a4.w += __shfl_xor(a4.w, 32);
    den0 += __shfl_xor(den0, 16); den0 += __shfl_xor(den0, 32);
    float inv = den0 > 0.f ? 1.f / den0 : 0.f;
    float4 bv = *(const float4*)&bias[c0];
    float a0 = a4.x * inv + bv.x;
    float a1 = a4.y * inv + bv.y;
    float a2 = a4.z * inv + bv.z;
    float a3 = a4.w * inv + bv.w;
    float mu = red16g(a0 + a1 + a2 + a3) * (1.f / 64.f);
    float d0 = a0 - mu, d1 = a1 - mu, d2 = a2 - mu, d3 = a3 - mu;
    float var = red16g(d0 * d0 + d1 * d1 + d2 * d2 + d3 * d3) * (1.f / 64.f);
    float rsq = rsqrtf(var + LNEPS);
    float4 gv = *(const float4*)&g[c0];
    float4 bb = *(const float4*)&b[c0];
    float o0 = d0 * rsq * gv.x + bb.x;
    float o1 = d1 * rsq * gv.y + bb.y;
    float o2 = d2 * rsq * gv.z + bb.z;
    float o3 = d3 * rsq * gv.w + bb.w;
    o0 = o0 > 0.f ? o0 : __expf(o0) - 1.f;
    o1 = o1 > 0.f ? o1 : __expf(o1) - 1.f;
    o2 = o2 > 0.f ? o2 : __expf(o2) - 1.f;
    o3 = o3 > 0.f ? o3 : __expf(o3) - 1.f;
    if (grp == 0)
        *(float4*)&out[(size_t)n * 64 + c0] = make_float4(o0, o1, o2, o3);
}

extern "C" void kernel_launch(void* const* d_in, const int* in_sizes, int n_in,
                              void* d_out, int out_size, void* d_ws, size_t ws_size,
                              hipStream_t stream) {
    const float* x    = (const float*)d_in[0];
    const float* ea   = (const float*)d_in[1];
    const float* W1l  = (const float*)d_in[2];
    const float* W1r  = (const float*)d_in[3];
    const float* W1e  = (const float*)d_in[4];
    const float* att1 = (const float*)d_in[5];
    const float* b1   = (const float*)d_in[6];
    const float* ln1g = (const float*)d_in[7];
    const float* ln1b = (const float*)d_in[8];
    const float* W2l  = (const float*)d_in[9];
    const float* W2r  = (const float*)d_in[10];
    const float* W2e  = (const float*)d_in[11];
    const float* att2 = (const float*)d_in[12];
    const float* b2   = (const float*)d_in[13];
    const float* ln2g = (const float*)d_in[14];
    const float* ln2b = (const float*)d_in[15];
    const int*   ei   = (const int*)d_in[16];
    float* out = (float*)d_out;
    float* ws  = (float*)d_ws;

    const size_t A = (size_t)NN * 128;
    float* xl1 = ws;                                   // N*128 f32
    float* h1  = ws + A;                               // N*128 f32
    float* xl2 = ws + 2 * A;                           // N*64 f32
    unsigned* xr1b = (unsigned*)(ws + 2 * A + (size_t)NN * 64);   // N*64 dwords (128 bf16)
    unsigned* xr2b = xr1b + (size_t)NN * 64;           // N*32 dwords (64 bf16)
    int2* cpack  = (int2*)(xr2b + (size_t)NN * 32);    // NE int2
    int* deg     = (int*)(cpack + (size_t)NE);         // NN
    int* rowstart= deg + NN;                           // NN+1
    int* cursor  = rowstart + NN + 1;                  // NN
    int* partial = cursor + NN;                        // NB

    hipMemsetAsync(deg, 0, NN * sizeof(int), stream);

    k_proj1<<<(NN + 3) / 4, 256, 0, stream>>>(x, W1l, W1r, xl1, xr1b);
    k_deg<<<(NE + 255) / 256, 256, 0, stream>>>(ei, deg);
    k_scan_block<<<NB, 256, 0, stream>>>(deg, rowstart, partial);
    k_scan_add<<<NB, 256, 0, stream>>>(partial, rowstart, cursor);
    k_scatter<<<(NE + 255) / 256, 256, 0, stream>>>(ei, ea, cursor, cpack);

    k_fused1<<<(NN + 3) / 4, 256, 0, stream>>>(rowstart, cpack, xl1, (const uint2*)xr1b,
                                               W1e, att1, b1, ln1g, ln1b, h1);
    k_proj2<<<(NN + 63) / 64, 256, 0, stream>>>(h1, W2l, W2r, xl2, xr2b);
    k_fused2<<<(NN + 3) / 4, 256, 0, stream>>>(rowstart, cpack, xl2, (const uint2*)xr2b,
                                               W2e, att2, b2, ln2g, ln2b, out);
}